// Round 1
// baseline (275.592 us; speedup 1.0000x reference)
//
#include <hip/hip_runtime.h>
#include <hip/hip_bf16.h>

#define BB   64      // batch
#define MM   512     // memories
#define SS   1024    // story len
#define EE   128     // embed
#define CC   10000   // classes
#define KCH  16      // m-chunks for stories reduction
#define MCH  (MM / KCH)   // 32 rows per chunk
#define CTILE 64     // classes per block in logits kernel

__device__ __forceinline__ float dot4(const float4 a, const float4 b) {
    return a.x * b.x + a.y * b.y + a.z * b.z + a.w * b.w;
}

// ---------------------------------------------------------------------------
// Kernel A: partial[k][b][s] = sum over m-chunk k of stories[b][m][s]
// grid = BB*KCH blocks, 256 threads; thread t owns float4 column t.
// Pure streaming read of 134 MB, coalesced 1 KB per wave instruction.
// ---------------------------------------------------------------------------
__global__ __launch_bounds__(256) void k_stories_reduce(
    const float4* __restrict__ stories, float4* __restrict__ partial) {
    const int S4 = SS / 4;  // 256
    const int blk = blockIdx.x;
    const int b = blk >> 4;          // / KCH
    const int k = blk & (KCH - 1);
    const int t = threadIdx.x;       // float4 col index 0..255
    const float4* src = stories + ((size_t)(b * MM + k * MCH) * S4 + t);
    float4 a0 = make_float4(0.f, 0.f, 0.f, 0.f);
    float4 a1 = a0, a2 = a0, a3 = a0;
    #pragma unroll
    for (int m = 0; m < MCH; m += 4) {
        float4 x0 = src[(size_t)(m + 0) * S4];
        float4 x1 = src[(size_t)(m + 1) * S4];
        float4 x2 = src[(size_t)(m + 2) * S4];
        float4 x3 = src[(size_t)(m + 3) * S4];
        a0.x += x0.x; a0.y += x0.y; a0.z += x0.z; a0.w += x0.w;
        a1.x += x1.x; a1.y += x1.y; a1.z += x1.z; a1.w += x1.w;
        a2.x += x2.x; a2.y += x2.y; a2.z += x2.z; a2.w += x2.w;
        a3.x += x3.x; a3.y += x3.y; a3.z += x3.z; a3.w += x3.w;
    }
    float4 r;
    r.x = (a0.x + a1.x) + (a2.x + a3.x);
    r.y = (a0.y + a1.y) + (a2.y + a3.y);
    r.z = (a0.z + a1.z) + (a2.z + a3.z);
    r.w = (a0.w + a1.w) + (a2.w + a3.w);
    partial[(size_t)(k * BB + b) * S4 + t] = r;
}

// ---------------------------------------------------------------------------
// Kernel B: per batch row b:
//   u0 = W1 @ q[b]; o = W2 @ ssum[b]; 3 hops of v = o + W3 @ u, u = v/||v||
// grid = BB blocks, 256 threads (4 waves). Wave-per-row dot products with
// coalesced float4 loads + 64-wide shuffle reduction.
// ---------------------------------------------------------------------------
__global__ __launch_bounds__(256) void k_embed_hops(
    const float* __restrict__ queries, const float* __restrict__ W1,
    const float* __restrict__ W2, const float* __restrict__ W3,
    const float* __restrict__ partial, float* __restrict__ u_out) {
    __shared__ float q_sh[SS];
    __shared__ float s_sh[SS];
    __shared__ float u_sh[EE];
    __shared__ float o_sh[EE];
    __shared__ float v_sh[EE];
    __shared__ float red_sh;
    const int b = blockIdx.x;
    const int t = threadIdx.x;
    const int S4 = SS / 4;

    // stage queries row and the 16-way partial sum of stories
    {
        const float4* q4 = (const float4*)queries + (size_t)b * S4;
        ((float4*)q_sh)[t] = q4[t];
        float4 acc = make_float4(0.f, 0.f, 0.f, 0.f);
        const float4* p4 = (const float4*)partial;
        #pragma unroll
        for (int k = 0; k < KCH; ++k) {
            float4 v = p4[(size_t)(k * BB + b) * S4 + t];
            acc.x += v.x; acc.y += v.y; acc.z += v.z; acc.w += v.w;
        }
        ((float4*)s_sh)[t] = acc;
    }
    __syncthreads();

    const int wid = t >> 6, lane = t & 63;
    for (int r = wid; r < 2 * EE; r += 4) {
        const float4* w4;
        const float4* x4;
        if (r < EE) {
            w4 = (const float4*)(W1 + (size_t)r * SS);
            x4 = (const float4*)q_sh;
        } else {
            w4 = (const float4*)(W2 + (size_t)(r - EE) * SS);
            x4 = (const float4*)s_sh;
        }
        float sum = 0.f;
        #pragma unroll
        for (int j = 0; j < 4; ++j) {
            float4 w = w4[lane + 64 * j];
            float4 x = x4[lane + 64 * j];
            sum += dot4(w, x);
        }
        #pragma unroll
        for (int off = 32; off > 0; off >>= 1)
            sum += __shfl_down(sum, off, 64);
        if (lane == 0) {
            if (r < EE) u_sh[r] = sum;
            else        o_sh[r - EE] = sum;
        }
    }
    __syncthreads();

    for (int hop = 0; hop < 3; ++hop) {
        if (t < EE) {
            const float4* w4 = (const float4*)(W3 + (size_t)t * EE);
            const float4* u4 = (const float4*)u_sh;
            float sum = 0.f;
            #pragma unroll
            for (int j = 0; j < EE / 4; ++j)
                sum += dot4(w4[j], u4[j]);
            v_sh[t] = o_sh[t] + sum;
        }
        __syncthreads();
        if (t < 64) {
            float v0 = v_sh[t], v1 = v_sh[t + 64];
            float s2 = v0 * v0 + v1 * v1;
            #pragma unroll
            for (int off = 32; off > 0; off >>= 1)
                s2 += __shfl_down(s2, off, 64);
            if (t == 0) red_sh = s2;
        }
        __syncthreads();
        float rn = 1.0f / fmaxf(sqrtf(red_sh), 1e-12f);
        if (t < EE) u_sh[t] = v_sh[t] * rn;
        __syncthreads();
    }

    if (t < EE / 4)
        ((float4*)(u_out + (size_t)b * EE))[t] = ((const float4*)u_sh)[t];
}

// ---------------------------------------------------------------------------
// Kernel C: logits[b][c] = dot(u[b], W4[c])   [64 x 10000]
// grid = ceil(CC/CTILE) blocks, 256 threads. Per-thread 4c x 4b register tile:
// 16 FMAs per (4 global + 4 LDS) float4 loads -> compute-bound.
// u staged in LDS with row stride 132 floats; b = bg + 16j keeps LDS reads
// spread across bank quads (<=2-way).
// ---------------------------------------------------------------------------
__global__ __launch_bounds__(256) void k_logits(
    const float* __restrict__ u_all, const float* __restrict__ W4,
    float* __restrict__ logits) {
    __shared__ float u_sh[BB * 132];
    const int t = threadIdx.x;

    {
        const float4* ug = (const float4*)u_all;
        for (int i = t; i < BB * (EE / 4); i += 256) {
            int bb = i >> 5, e4 = i & 31;
            ((float4*)(u_sh + bb * 132))[e4] = ug[i];
        }
    }
    __syncthreads();

    const int bg = t & 15;   // b = bg + 16*j
    const int cg = t >> 4;   // c = c0 + cg*4 + i
    const int cbase = blockIdx.x * CTILE + cg * 4;

    const float4* wr0 = (const float4*)(W4 + (size_t)min(cbase + 0, CC - 1) * EE);
    const float4* wr1 = (const float4*)(W4 + (size_t)min(cbase + 1, CC - 1) * EE);
    const float4* wr2 = (const float4*)(W4 + (size_t)min(cbase + 2, CC - 1) * EE);
    const float4* wr3 = (const float4*)(W4 + (size_t)min(cbase + 3, CC - 1) * EE);
    const float4* u0 = (const float4*)(u_sh + (bg + 0)  * 132);
    const float4* u1 = (const float4*)(u_sh + (bg + 16) * 132);
    const float4* u2 = (const float4*)(u_sh + (bg + 32) * 132);
    const float4* u3 = (const float4*)(u_sh + (bg + 48) * 132);

    float acc[4][4];
    #pragma unroll
    for (int i = 0; i < 4; ++i)
        #pragma unroll
        for (int j = 0; j < 4; ++j) acc[i][j] = 0.f;

    #pragma unroll 4
    for (int e4 = 0; e4 < EE / 4; ++e4) {
        float4 w0 = wr0[e4], w1 = wr1[e4], w2 = wr2[e4], w3 = wr3[e4];
        float4 x0 = u0[e4], x1 = u1[e4], x2 = u2[e4], x3 = u3[e4];
        acc[0][0] += dot4(w0, x0); acc[0][1] += dot4(w0, x1);
        acc[0][2] += dot4(w0, x2); acc[0][3] += dot4(w0, x3);
        acc[1][0] += dot4(w1, x0); acc[1][1] += dot4(w1, x1);
        acc[1][2] += dot4(w1, x2); acc[1][3] += dot4(w1, x3);
        acc[2][0] += dot4(w2, x0); acc[2][1] += dot4(w2, x1);
        acc[2][2] += dot4(w2, x2); acc[2][3] += dot4(w2, x3);
        acc[3][0] += dot4(w3, x0); acc[3][1] += dot4(w3, x1);
        acc[3][2] += dot4(w3, x2); acc[3][3] += dot4(w3, x3);
    }

    #pragma unroll
    for (int i = 0; i < 4; ++i) {
        int c = cbase + i;
        if (c < CC) {
            #pragma unroll
            for (int j = 0; j < 4; ++j) {
                int bb = bg + 16 * j;
                logits[(size_t)bb * CC + c] = acc[i][j];
            }
        }
    }
}

// ---------------------------------------------------------------------------
// Kernel D: row softmax over CC. grid = BB blocks, 256 threads.
// Row staged in LDS (40 KB): max -> exp+sum -> scale, single global RW pass.
// ---------------------------------------------------------------------------
__global__ __launch_bounds__(256) void k_softmax(
    const float* __restrict__ logits, float* __restrict__ out) {
    __shared__ float row[CC];
    __shared__ float redm[4];
    __shared__ float reds[4];
    const int b = blockIdx.x, t = threadIdx.x;
    const int wid = t >> 6, lane = t & 63;
    const int C4 = CC / 4;  // 2500

    const float4* src = (const float4*)(logits + (size_t)b * CC);
    float4* row4 = (float4*)row;

    float lmax = -3.4e38f;
    for (int i = t; i < C4; i += 256) {
        float4 v = src[i];
        row4[i] = v;
        lmax = fmaxf(lmax, fmaxf(fmaxf(v.x, v.y), fmaxf(v.z, v.w)));
    }
    #pragma unroll
    for (int off = 32; off > 0; off >>= 1)
        lmax = fmaxf(lmax, __shfl_down(lmax, off, 64));
    if (lane == 0) redm[wid] = lmax;
    __syncthreads();
    const float m = fmaxf(fmaxf(redm[0], redm[1]), fmaxf(redm[2], redm[3]));

    float lsum = 0.f;
    for (int i = t; i < C4; i += 256) {
        float4 v = row4[i];
        v.x = expf(v.x - m); v.y = expf(v.y - m);
        v.z = expf(v.z - m); v.w = expf(v.w - m);
        row4[i] = v;
        lsum += (v.x + v.y) + (v.z + v.w);
    }
    #pragma unroll
    for (int off = 32; off > 0; off >>= 1)
        lsum += __shfl_down(lsum, off, 64);
    if (lane == 0) reds[wid] = lsum;
    __syncthreads();
    const float inv = 1.0f / ((reds[0] + reds[1]) + (reds[2] + reds[3]));

    float4* dst = (float4*)(out + (size_t)b * CC);
    for (int i = t; i < C4; i += 256) {
        float4 v = row4[i];
        v.x *= inv; v.y *= inv; v.z *= inv; v.w *= inv;
        dst[i] = v;
    }
}

// ---------------------------------------------------------------------------
extern "C" void kernel_launch(void* const* d_in, const int* in_sizes, int n_in,
                              void* d_out, int out_size, void* d_ws, size_t ws_size,
                              hipStream_t stream) {
    const float* stories = (const float*)d_in[0];
    const float* queries = (const float*)d_in[1];
    const float* W1 = (const float*)d_in[2];
    const float* W2 = (const float*)d_in[3];
    const float* W3 = (const float*)d_in[4];
    const float* W4 = (const float*)d_in[5];
    float* out = (float*)d_out;

    // workspace layout (floats): partial[KCH][BB][SS] | u_all[BB][EE] | logits[BB][CC]
    float* partial = (float*)d_ws;
    float* u_all   = partial + (size_t)KCH * BB * SS;   // +4 MB
    float* logits  = u_all + (size_t)BB * EE;           // +32 KB

    k_stories_reduce<<<BB * KCH, 256, 0, stream>>>(
        (const float4*)stories, (float4*)partial);
    k_embed_hops<<<BB, 256, 0, stream>>>(queries, W1, W2, W3, partial, u_all);
    k_logits<<<(CC + CTILE - 1) / CTILE, 256, 0, stream>>>(u_all, W4, logits);
    k_softmax<<<BB, 256, 0, stream>>>(logits, out);
}

// Round 2
// 243.584 us; speedup vs baseline: 1.1314x; 1.1314x over previous
//
#include <hip/hip_runtime.h>
#include <hip/hip_bf16.h>

#define BB   64      // batch
#define MM   512     // memories
#define SS   1024    // story len
#define EE   128     // embed
#define CC   10000   // classes
#define KCH  16      // m-chunks for stories reduction
#define MCH  (MM / KCH)   // 32 rows per chunk
#define RCH  8       // row-chunks per batch in k_uo (256 rows / 32)
#define CTILE 32     // classes per block in logits kernel

__device__ __forceinline__ float dot4(const float4 a, const float4 b) {
    return a.x * b.x + a.y * b.y + a.z * b.z + a.w * b.w;
}

// ---------------------------------------------------------------------------
// Kernel A: partial[k][b][s] = sum over m-chunk k of stories[b][m][s]
// grid = BB*KCH = 1024 blocks, 256 threads; thread t owns float4 column t.
// Pure streaming read of 134 MB, coalesced 1 KB per wave instruction.
// ---------------------------------------------------------------------------
__global__ __launch_bounds__(256) void k_stories_reduce(
    const float4* __restrict__ stories, float4* __restrict__ partial) {
    const int S4 = SS / 4;  // 256
    const int blk = blockIdx.x;
    const int b = blk >> 4;          // / KCH
    const int k = blk & (KCH - 1);
    const int t = threadIdx.x;       // float4 col index 0..255
    const float4* src = stories + ((size_t)(b * MM + k * MCH) * S4 + t);
    float4 a0 = make_float4(0.f, 0.f, 0.f, 0.f);
    float4 a1 = a0, a2 = a0, a3 = a0;
    #pragma unroll
    for (int m = 0; m < MCH; m += 4) {
        float4 x0 = src[(size_t)(m + 0) * S4];
        float4 x1 = src[(size_t)(m + 1) * S4];
        float4 x2 = src[(size_t)(m + 2) * S4];
        float4 x3 = src[(size_t)(m + 3) * S4];
        a0.x += x0.x; a0.y += x0.y; a0.z += x0.z; a0.w += x0.w;
        a1.x += x1.x; a1.y += x1.y; a1.z += x1.z; a1.w += x1.w;
        a2.x += x2.x; a2.y += x2.y; a2.z += x2.z; a2.w += x2.w;
        a3.x += x3.x; a3.y += x3.y; a3.z += x3.z; a3.w += x3.w;
    }
    float4 r;
    r.x = (a0.x + a1.x) + (a2.x + a3.x);
    r.y = (a0.y + a1.y) + (a2.y + a3.y);
    r.z = (a0.z + a1.z) + (a2.z + a3.z);
    r.w = (a0.w + a1.w) + (a2.w + a3.w);
    partial[(size_t)(k * BB + b) * S4 + t] = r;
}

// ---------------------------------------------------------------------------
// Kernel B1: uo[b][r] for r in [0,256): r<128 -> u0 = W1@q[b], else o = W2@ssum[b]
// grid = BB*RCH = 512 blocks (b, 32-row chunk), 256 threads (4 waves x 8 rows).
// Wave-per-row dots: coalesced float4 + 64-wide shuffle reduce.
// ---------------------------------------------------------------------------
__global__ __launch_bounds__(256) void k_uo(
    const float* __restrict__ queries, const float* __restrict__ W1,
    const float* __restrict__ W2, const float* __restrict__ partial,
    float* __restrict__ uo) {
    __shared__ float x_sh[2][SS];   // [0]=q row, [1]=story sum  (8 KB)
    const int b = blockIdx.x >> 3;
    const int chunk = blockIdx.x & (RCH - 1);
    const int t = threadIdx.x;
    const int S4 = SS / 4;

    {
        const float4* q4 = (const float4*)queries + (size_t)b * S4;
        ((float4*)x_sh[0])[t] = q4[t];
        float4 acc = make_float4(0.f, 0.f, 0.f, 0.f);
        const float4* p4 = (const float4*)partial;
        #pragma unroll
        for (int k = 0; k < KCH; ++k) {
            float4 v = p4[(size_t)(k * BB + b) * S4 + t];
            acc.x += v.x; acc.y += v.y; acc.z += v.z; acc.w += v.w;
        }
        ((float4*)x_sh[1])[t] = acc;
    }
    __syncthreads();

    const int wid = t >> 6, lane = t & 63;
    const int rbase = chunk * 32 + wid * 8;   // 8 consecutive rows per wave
    #pragma unroll
    for (int i = 0; i < 8; ++i) {
        const int r = rbase + i;              // global row 0..255
        const int sel = (r >= EE);
        const float4* w4 = (const float4*)((sel ? W2 + (size_t)(r - EE) * SS
                                                : W1 + (size_t)r * SS));
        const float4* x4 = (const float4*)x_sh[sel];
        float sum = 0.f;
        #pragma unroll
        for (int j = 0; j < 4; ++j)
            sum += dot4(w4[lane + 64 * j], x4[lane + 64 * j]);
        #pragma unroll
        for (int off = 32; off > 0; off >>= 1)
            sum += __shfl_down(sum, off, 64);
        if (lane == 0) uo[(size_t)b * 256 + r] = sum;
    }
}

// ---------------------------------------------------------------------------
// Kernel B2: 3 hops: v = o + W3@u; u = v/max(||v||,eps). grid=BB, 128 threads.
// ---------------------------------------------------------------------------
__global__ __launch_bounds__(128) void k_hops(
    const float* __restrict__ W3, const float* __restrict__ uo,
    float* __restrict__ u_out) {
    __shared__ float u_sh[EE];
    __shared__ float red[2];
    const int b = blockIdx.x, t = threadIdx.x;
    const int wid = t >> 6, lane = t & 63;

    const float o_r = uo[(size_t)b * 256 + EE + t];
    u_sh[t] = uo[(size_t)b * 256 + t];
    __syncthreads();

    const float4* w4 = (const float4*)(W3 + (size_t)t * EE);
    float u_new = 0.f;
    for (int hop = 0; hop < 3; ++hop) {
        float sum = 0.f;
        #pragma unroll
        for (int j = 0; j < EE / 4; ++j)
            sum += dot4(w4[j], ((const float4*)u_sh)[j]);
        const float v = o_r + sum;
        float s2 = v * v;
        #pragma unroll
        for (int off = 32; off > 0; off >>= 1)
            s2 += __shfl_down(s2, off, 64);
        if (lane == 0) red[wid] = s2;
        __syncthreads();                       // dots done + red visible
        const float rn = 1.0f / fmaxf(sqrtf(red[0] + red[1]), 1e-12f);
        u_new = v * rn;
        u_sh[t] = u_new;
        __syncthreads();                       // u_sh updated for next hop
    }
    u_out[(size_t)b * EE + t] = u_new;
}

// ---------------------------------------------------------------------------
// Kernel C: logits[b][c] = dot(u[b], W4[c])   [64 x 10000]
// grid = ceil(CC/32) = 313 blocks, 128 threads. 4c x 4b register tile:
// 16 FMAs per (4 global + 4 LDS) float4 loads. All 256 CUs covered.
// ---------------------------------------------------------------------------
__global__ __launch_bounds__(128) void k_logits(
    const float* __restrict__ u_all, const float* __restrict__ W4,
    float* __restrict__ logits) {
    __shared__ float u_sh[BB * 132];
    const int t = threadIdx.x;

    {
        const float4* ug = (const float4*)u_all;
        for (int i = t; i < BB * (EE / 4); i += 128) {
            int bb = i >> 5, e4 = i & 31;
            ((float4*)(u_sh + bb * 132))[e4] = ug[i];
        }
    }
    __syncthreads();

    const int bg = t & 15;   // b = bg + 16*j
    const int cg = t >> 4;   // 0..7
    const int cbase = blockIdx.x * CTILE + cg * 4;

    const float4* wr0 = (const float4*)(W4 + (size_t)min(cbase + 0, CC - 1) * EE);
    const float4* wr1 = (const float4*)(W4 + (size_t)min(cbase + 1, CC - 1) * EE);
    const float4* wr2 = (const float4*)(W4 + (size_t)min(cbase + 2, CC - 1) * EE);
    const float4* wr3 = (const float4*)(W4 + (size_t)min(cbase + 3, CC - 1) * EE);
    const float4* u0 = (const float4*)(u_sh + (bg + 0)  * 132);
    const float4* u1 = (const float4*)(u_sh + (bg + 16) * 132);
    const float4* u2 = (const float4*)(u_sh + (bg + 32) * 132);
    const float4* u3 = (const float4*)(u_sh + (bg + 48) * 132);

    float acc[4][4];
    #pragma unroll
    for (int i = 0; i < 4; ++i)
        #pragma unroll
        for (int j = 0; j < 4; ++j) acc[i][j] = 0.f;

    #pragma unroll 4
    for (int e4 = 0; e4 < EE / 4; ++e4) {
        float4 w0 = wr0[e4], w1 = wr1[e4], w2 = wr2[e4], w3 = wr3[e4];
        float4 x0 = u0[e4], x1 = u1[e4], x2 = u2[e4], x3 = u3[e4];
        acc[0][0] += dot4(w0, x0); acc[0][1] += dot4(w0, x1);
        acc[0][2] += dot4(w0, x2); acc[0][3] += dot4(w0, x3);
        acc[1][0] += dot4(w1, x0); acc[1][1] += dot4(w1, x1);
        acc[1][2] += dot4(w1, x2); acc[1][3] += dot4(w1, x3);
        acc[2][0] += dot4(w2, x0); acc[2][1] += dot4(w2, x1);
        acc[2][2] += dot4(w2, x2); acc[2][3] += dot4(w2, x3);
        acc[3][0] += dot4(w3, x0); acc[3][1] += dot4(w3, x1);
        acc[3][2] += dot4(w3, x2); acc[3][3] += dot4(w3, x3);
    }

    #pragma unroll
    for (int i = 0; i < 4; ++i) {
        int c = cbase + i;
        if (c < CC) {
            #pragma unroll
            for (int j = 0; j < 4; ++j) {
                int bb = bg + 16 * j;
                logits[(size_t)bb * CC + c] = acc[i][j];
            }
        }
    }
}

// ---------------------------------------------------------------------------
// Kernel D: row softmax over CC. grid = BB blocks, 256 threads.
// Row staged in LDS (40 KB): max -> exp+sum -> scale, single global RW pass.
// ---------------------------------------------------------------------------
__global__ __launch_bounds__(256) void k_softmax(
    const float* __restrict__ logits, float* __restrict__ out) {
    __shared__ float row[CC];
    __shared__ float redm[4];
    __shared__ float reds[4];
    const int b = blockIdx.x, t = threadIdx.x;
    const int wid = t >> 6, lane = t & 63;
    const int C4 = CC / 4;  // 2500

    const float4* src = (const float4*)(logits + (size_t)b * CC);
    float4* row4 = (float4*)row;

    float lmax = -3.4e38f;
    for (int i = t; i < C4; i += 256) {
        float4 v = src[i];
        row4[i] = v;
        lmax = fmaxf(lmax, fmaxf(fmaxf(v.x, v.y), fmaxf(v.z, v.w)));
    }
    #pragma unroll
    for (int off = 32; off > 0; off >>= 1)
        lmax = fmaxf(lmax, __shfl_down(lmax, off, 64));
    if (lane == 0) redm[wid] = lmax;
    __syncthreads();
    const float m = fmaxf(fmaxf(redm[0], redm[1]), fmaxf(redm[2], redm[3]));

    float lsum = 0.f;
    for (int i = t; i < C4; i += 256) {
        float4 v = row4[i];
        v.x = expf(v.x - m); v.y = expf(v.y - m);
        v.z = expf(v.z - m); v.w = expf(v.w - m);
        row4[i] = v;
        lsum += (v.x + v.y) + (v.z + v.w);
    }
    #pragma unroll
    for (int off = 32; off > 0; off >>= 1)
        lsum += __shfl_down(lsum, off, 64);
    if (lane == 0) reds[wid] = lsum;
    __syncthreads();
    const float inv = 1.0f / ((reds[0] + reds[1]) + (reds[2] + reds[3]));

    float4* dst = (float4*)(out + (size_t)b * CC);
    for (int i = t; i < C4; i += 256) {
        float4 v = row4[i];
        v.x *= inv; v.y *= inv; v.z *= inv; v.w *= inv;
        dst[i] = v;
    }
}

// ---------------------------------------------------------------------------
extern "C" void kernel_launch(void* const* d_in, const int* in_sizes, int n_in,
                              void* d_out, int out_size, void* d_ws, size_t ws_size,
                              hipStream_t stream) {
    const float* stories = (const float*)d_in[0];
    const float* queries = (const float*)d_in[1];
    const float* W1 = (const float*)d_in[2];
    const float* W2 = (const float*)d_in[3];
    const float* W3 = (const float*)d_in[4];
    const float* W4 = (const float*)d_in[5];
    float* out = (float*)d_out;

    // ws layout (floats):
    // partial[KCH][BB][SS] | uo[BB][256] | u_all[BB][EE] | logits[BB][CC]
    float* partial = (float*)d_ws;
    float* uo      = partial + (size_t)KCH * BB * SS;   // +4 MB
    float* u_all   = uo + (size_t)BB * 256;             // +64 KB
    float* logits  = u_all + (size_t)BB * EE;           // +32 KB

    k_stories_reduce<<<BB * KCH, 256, 0, stream>>>(
        (const float4*)stories, (float4*)partial);
    k_uo<<<BB * RCH, 256, 0, stream>>>(queries, W1, W2, partial, uo);
    k_hops<<<BB, 128, 0, stream>>>(W3, uo, u_all);
    k_logits<<<(CC + CTILE - 1) / CTILE, 128, 0, stream>>>(u_all, W4, logits);
    k_softmax<<<BB, 256, 0, stream>>>(logits, out);
}

// Round 3
// 231.461 us; speedup vs baseline: 1.1907x; 1.0524x over previous
//
#include <hip/hip_runtime.h>
#include <hip/hip_bf16.h>

#define BB   64      // batch
#define MM   512     // memories
#define SS   1024    // story len
#define EE   128     // embed
#define CC   10000   // classes
#define KCH  16      // m-chunks for stories reduction
#define MCH  (MM / KCH)   // 32 rows per chunk
#define RCH  16      // row-chunks per batch in k_uo (256 rows / 16)
#define CTILE 16     // classes per block in logits kernel (10000 = 625*16)

__device__ __forceinline__ float dot4(const float4 a, const float4 b) {
    return a.x * b.x + a.y * b.y + a.z * b.z + a.w * b.w;
}

// ---------------------------------------------------------------------------
// Kernel A: partial[k][b][s] = sum over m-chunk k of stories[b][m][s]
// grid = BB*KCH = 1024 blocks, 256 threads; thread t owns float4 column t.
// Pure streaming read of 134 MB, coalesced 1 KB per wave instruction.
// ---------------------------------------------------------------------------
__global__ __launch_bounds__(256) void k_stories_reduce(
    const float4* __restrict__ stories, float4* __restrict__ partial) {
    const int S4 = SS / 4;  // 256
    const int blk = blockIdx.x;
    const int b = blk >> 4;          // / KCH
    const int k = blk & (KCH - 1);
    const int t = threadIdx.x;       // float4 col index 0..255
    const float4* src = stories + ((size_t)(b * MM + k * MCH) * S4 + t);
    float4 a0 = make_float4(0.f, 0.f, 0.f, 0.f);
    float4 a1 = a0, a2 = a0, a3 = a0;
    #pragma unroll
    for (int m = 0; m < MCH; m += 4) {
        float4 x0 = src[(size_t)(m + 0) * S4];
        float4 x1 = src[(size_t)(m + 1) * S4];
        float4 x2 = src[(size_t)(m + 2) * S4];
        float4 x3 = src[(size_t)(m + 3) * S4];
        a0.x += x0.x; a0.y += x0.y; a0.z += x0.z; a0.w += x0.w;
        a1.x += x1.x; a1.y += x1.y; a1.z += x1.z; a1.w += x1.w;
        a2.x += x2.x; a2.y += x2.y; a2.z += x2.z; a2.w += x2.w;
        a3.x += x3.x; a3.y += x3.y; a3.z += x3.z; a3.w += x3.w;
    }
    float4 r;
    r.x = (a0.x + a1.x) + (a2.x + a3.x);
    r.y = (a0.y + a1.y) + (a2.y + a3.y);
    r.z = (a0.z + a1.z) + (a2.z + a3.z);
    r.w = (a0.w + a1.w) + (a2.w + a3.w);
    partial[(size_t)(k * BB + b) * S4 + t] = r;
}

// ---------------------------------------------------------------------------
// Kernel A2: ssum[b][s] = sum_k partial[k][b][s]. grid = 256 blocks x 64 thr.
// Collapses the 16 partials once so k_uo doesn't re-reduce them per block.
// ---------------------------------------------------------------------------
__global__ __launch_bounds__(64) void k_ssum(
    const float4* __restrict__ partial, float4* __restrict__ ssum) {
    const int S4 = SS / 4;
    const int b = blockIdx.x >> 2;
    const int col = (blockIdx.x & 3) * 64 + threadIdx.x;   // 0..255
    float4 acc = make_float4(0.f, 0.f, 0.f, 0.f);
    #pragma unroll
    for (int k = 0; k < KCH; ++k) {
        float4 v = partial[(size_t)(k * BB + b) * S4 + col];
        acc.x += v.x; acc.y += v.y; acc.z += v.z; acc.w += v.w;
    }
    ssum[(size_t)b * S4 + col] = acc;
}

// ---------------------------------------------------------------------------
// Kernel B1: uo[b][r], r<128 -> u0 = W1@q[b]; r>=128 -> o = W2@ssum[b]
// grid = BB*RCH = 1024 blocks (b, 16-row chunk), 256 threads (4 waves x 4 rows).
// Wave-per-row dots: coalesced float4 + 64-wide shuffle reduce.
// ---------------------------------------------------------------------------
__global__ __launch_bounds__(256) void k_uo(
    const float* __restrict__ queries, const float* __restrict__ W1,
    const float* __restrict__ W2, const float* __restrict__ ssum,
    float* __restrict__ uo) {
    __shared__ float x_sh[2][SS];   // [0]=q row, [1]=story sum  (8 KB)
    const int b = blockIdx.x >> 4;
    const int chunk = blockIdx.x & (RCH - 1);
    const int t = threadIdx.x;
    const int S4 = SS / 4;

    ((float4*)x_sh[0])[t] = ((const float4*)queries)[(size_t)b * S4 + t];
    ((float4*)x_sh[1])[t] = ((const float4*)ssum)[(size_t)b * S4 + t];
    __syncthreads();

    const int wid = t >> 6, lane = t & 63;
    const int rbase = chunk * 16 + wid * 4;   // 4 consecutive rows per wave
    #pragma unroll
    for (int i = 0; i < 4; ++i) {
        const int r = rbase + i;              // global row 0..255
        const int sel = (r >= EE);
        const float4* w4 = (const float4*)(sel ? W2 + (size_t)(r - EE) * SS
                                               : W1 + (size_t)r * SS);
        const float4* x4 = (const float4*)x_sh[sel];
        float sum = 0.f;
        #pragma unroll
        for (int j = 0; j < 4; ++j)
            sum += dot4(w4[lane + 64 * j], x4[lane + 64 * j]);
        #pragma unroll
        for (int off = 32; off > 0; off >>= 1)
            sum += __shfl_down(sum, off, 64);
        if (lane == 0) uo[(size_t)b * 256 + r] = sum;
    }
}

// ---------------------------------------------------------------------------
// Kernel B2: 3 hops: v = o + W3@u; u = v/max(||v||,eps). grid=BB, 128 threads.
// ---------------------------------------------------------------------------
__global__ __launch_bounds__(128) void k_hops(
    const float* __restrict__ W3, const float* __restrict__ uo,
    float* __restrict__ u_out) {
    __shared__ float u_sh[EE];
    __shared__ float red[2];
    const int b = blockIdx.x, t = threadIdx.x;
    const int wid = t >> 6, lane = t & 63;

    const float o_r = uo[(size_t)b * 256 + EE + t];
    u_sh[t] = uo[(size_t)b * 256 + t];
    __syncthreads();

    const float4* w4 = (const float4*)(W3 + (size_t)t * EE);
    float u_new = 0.f;
    for (int hop = 0; hop < 3; ++hop) {
        float sum = 0.f;
        #pragma unroll
        for (int j = 0; j < EE / 4; ++j)
            sum += dot4(w4[j], ((const float4*)u_sh)[j]);
        const float v = o_r + sum;
        float s2 = v * v;
        #pragma unroll
        for (int off = 32; off > 0; off >>= 1)
            s2 += __shfl_down(s2, off, 64);
        if (lane == 0) red[wid] = s2;
        __syncthreads();                       // dots done + red visible
        const float rn = 1.0f / fmaxf(sqrtf(red[0] + red[1]), 1e-12f);
        u_new = v * rn;
        u_sh[t] = u_new;
        __syncthreads();                       // u_sh updated for next hop
    }
    u_out[(size_t)b * EE + t] = u_new;
}

// ---------------------------------------------------------------------------
// Kernel C: logits[b][c] = dot(u[b], W4[c])   [64 x 10000]
// grid = 625 blocks (16 classes each, exact), 128 threads. 2c x 4b register
// tile: 8 dot4 per (2 global + 4 LDS) float4 loads; 1250 waves across the
// chip's 1024 SIMDs, ~2048 FMA-instrs per wave.
// ---------------------------------------------------------------------------
__global__ __launch_bounds__(128) void k_logits(
    const float* __restrict__ u_all, const float* __restrict__ W4,
    float* __restrict__ logits) {
    __shared__ float u_sh[BB * 132];
    const int t = threadIdx.x;

    {
        const float4* ug = (const float4*)u_all;
        for (int i = t; i < BB * (EE / 4); i += 128) {
            int bb = i >> 5, e4 = i & 31;
            ((float4*)(u_sh + bb * 132))[e4] = ug[i];
        }
    }
    __syncthreads();

    const int bg = t & 15;   // b = bg + 16*j
    const int cg = t >> 4;   // 0..7
    const int cbase = blockIdx.x * CTILE + cg * 2;   // always < CC-1

    const float4* wr0 = (const float4*)(W4 + (size_t)(cbase + 0) * EE);
    const float4* wr1 = (const float4*)(W4 + (size_t)(cbase + 1) * EE);
    const float4* u0 = (const float4*)(u_sh + (bg + 0)  * 132);
    const float4* u1 = (const float4*)(u_sh + (bg + 16) * 132);
    const float4* u2 = (const float4*)(u_sh + (bg + 32) * 132);
    const float4* u3 = (const float4*)(u_sh + (bg + 48) * 132);

    float acc[2][4];
    #pragma unroll
    for (int i = 0; i < 2; ++i)
        #pragma unroll
        for (int j = 0; j < 4; ++j) acc[i][j] = 0.f;

    #pragma unroll 8
    for (int e4 = 0; e4 < EE / 4; ++e4) {
        float4 w0 = wr0[e4], w1 = wr1[e4];
        float4 x0 = u0[e4], x1 = u1[e4], x2 = u2[e4], x3 = u3[e4];
        acc[0][0] += dot4(w0, x0); acc[0][1] += dot4(w0, x1);
        acc[0][2] += dot4(w0, x2); acc[0][3] += dot4(w0, x3);
        acc[1][0] += dot4(w1, x0); acc[1][1] += dot4(w1, x1);
        acc[1][2] += dot4(w1, x2); acc[1][3] += dot4(w1, x3);
    }

    #pragma unroll
    for (int i = 0; i < 2; ++i) {
        #pragma unroll
        for (int j = 0; j < 4; ++j) {
            int bb = bg + 16 * j;
            logits[(size_t)bb * CC + cbase + i] = acc[i][j];
        }
    }
}

// ---------------------------------------------------------------------------
// Kernel D: row softmax over CC. grid = BB blocks, 1024 threads (16 waves —
// 4x the memory-level parallelism of the 256-thread version).
// Row staged in LDS (40 KB): max -> exp+sum -> scale, single global RW pass.
// ---------------------------------------------------------------------------
__global__ __launch_bounds__(1024) void k_softmax(
    const float* __restrict__ logits, float* __restrict__ out) {
    __shared__ float row[CC];
    __shared__ float redm[16];
    __shared__ float reds[16];
    const int b = blockIdx.x, t = threadIdx.x;
    const int wid = t >> 6, lane = t & 63;
    const int C4 = CC / 4;  // 2500

    const float4* src = (const float4*)(logits + (size_t)b * CC);
    float4* row4 = (float4*)row;

    float lmax = -3.4e38f;
    for (int i = t; i < C4; i += 1024) {
        float4 v = src[i];
        row4[i] = v;
        lmax = fmaxf(lmax, fmaxf(fmaxf(v.x, v.y), fmaxf(v.z, v.w)));
    }
    #pragma unroll
    for (int off = 32; off > 0; off >>= 1)
        lmax = fmaxf(lmax, __shfl_down(lmax, off, 64));
    if (lane == 0) redm[wid] = lmax;
    __syncthreads();
    float m = redm[0];
    #pragma unroll
    for (int k = 1; k < 16; ++k) m = fmaxf(m, redm[k]);

    float lsum = 0.f;
    for (int i = t; i < C4; i += 1024) {
        float4 v = row4[i];
        v.x = expf(v.x - m); v.y = expf(v.y - m);
        v.z = expf(v.z - m); v.w = expf(v.w - m);
        row4[i] = v;
        lsum += (v.x + v.y) + (v.z + v.w);
    }
    #pragma unroll
    for (int off = 32; off > 0; off >>= 1)
        lsum += __shfl_down(lsum, off, 64);
    if (lane == 0) reds[wid] = lsum;
    __syncthreads();
    float s = 0.f;
    #pragma unroll
    for (int k = 0; k < 16; ++k) s += reds[k];
    const float inv = 1.0f / s;

    float4* dst = (float4*)(out + (size_t)b * CC);
    for (int i = t; i < C4; i += 1024) {
        float4 v = row4[i];
        v.x *= inv; v.y *= inv; v.z *= inv; v.w *= inv;
        dst[i] = v;
    }
}

// ---------------------------------------------------------------------------
extern "C" void kernel_launch(void* const* d_in, const int* in_sizes, int n_in,
                              void* d_out, int out_size, void* d_ws, size_t ws_size,
                              hipStream_t stream) {
    const float* stories = (const float*)d_in[0];
    const float* queries = (const float*)d_in[1];
    const float* W1 = (const float*)d_in[2];
    const float* W2 = (const float*)d_in[3];
    const float* W3 = (const float*)d_in[4];
    const float* W4 = (const float*)d_in[5];
    float* out = (float*)d_out;

    // ws layout (floats):
    // partial[KCH][BB][SS] | ssum[BB][SS] | uo[BB][256] | u_all[BB][EE] | logits[BB][CC]
    float* partial = (float*)d_ws;
    float* ssum    = partial + (size_t)KCH * BB * SS;   // +4 MB
    float* uo      = ssum + (size_t)BB * SS;            // +256 KB
    float* u_all   = uo + (size_t)BB * 256;             // +64 KB
    float* logits  = u_all + (size_t)BB * EE;           // +32 KB

    k_stories_reduce<<<BB * KCH, 256, 0, stream>>>(
        (const float4*)stories, (float4*)partial);
    k_ssum<<<BB * 4, 64, 0, stream>>>((const float4*)partial, (float4*)ssum);
    k_uo<<<BB * RCH, 256, 0, stream>>>(queries, W1, W2, ssum, uo);
    k_hops<<<BB, 128, 0, stream>>>(W3, uo, u_all);
    k_logits<<<CC / CTILE, 128, 0, stream>>>(u_all, W4, logits);
    k_softmax<<<BB, 1024, 0, stream>>>(logits, out);
}